// Round 2
// baseline (914.277 us; speedup 1.0000x reference)
//
#include <hip/hip_runtime.h>
#include <math.h>

// TopKGating: logits = x @ W^T + b  -> softmax(8) -> top-2 (indices, values)
// x: [131072, 1024] f32, W: [8, 1024] f32, b: [8] f32
// out: [N*2] indices (as float) then [N*2] values, flat concat.
//
// R2: wave-autonomous deep pipeline.
//  - NO __syncthreads. Each wave owns 64 tokens and a private LDS region;
//    within-wave LDS RAW/WAR is safe (lockstep wave + in-order DS pipe +
//    compiler-ordered aliasing LDS ops), so no barrier-forced vmcnt(0)
//    drain ever happens. This was the 19%-of-peak killer in R0/R1: all
//    waves lockstepped into burst-issue/ drain sawtooth.
//  - P=4 chunk register pipeline: 32 outstanding 1KB loads per wave keep
//    memory issue continuous; compiler emits counted vmcnt per buffer.
//  - DC=32 floats/chunk: staging instrs are 8 lanes x 128B = full cache
//    lines, fully coalesced.

#define NUM_TOKENS 131072
#define DIM        1024
#define NE         8
#define TPB        256            // 4 waves, thread == token
#define DC         32             // floats per token per chunk
#define NCH        (DIM / DC)     // 32 chunks
#define PD         4              // pipeline depth (chunks in flight); 32 % 4 == 0
#define RS4        9              // LDS row stride in float4 (8 data + 1 pad
                                  // = 36 floats; residue-4 bank pattern,
                                  // conflict-free for b128 ops)

__global__ __launch_bounds__(TPB)
void topk_gating_kernel(const float* __restrict__ x,
                        const float* __restrict__ W,
                        const float* __restrict__ b,
                        float* __restrict__ out)
{
    __shared__ float4 lds4[4][64 * RS4];   // 4 waves x 9216 B = 36864 B
    const int t    = threadIdx.x;
    const int lane = t & 63;
    const int w    = t >> 6;
    const int tok0 = blockIdx.x * TPB;

    const float4* x4 = (const float4*)x;   // [N, 256]
    const float4* W4 = (const float4*)W;   // [8, 256]
    float4* lw = lds4[w];                  // this wave's private region

    // Per-lane staging coords (fixed): instr i covers token rows i*8..i*8+7,
    // 8 lanes x 128B contiguous per row -> full-line coalescing.
    const int rb  = lane >> 3;             // row within 8-row group
    const int c4  = lane & 7;              // float4 col within chunk
    const int row0 = tok0 + w * 64;        // this wave's first token

    float acc[NE];
#pragma unroll
    for (int e = 0; e < NE; ++e) acc[e] = 0.f;

    float4 pre[PD][8];

    // Prologue: issue chunks 0..PD-1.
#pragma unroll
    for (int p = 0; p < PD; ++p)
#pragma unroll
        for (int i = 0; i < 8; ++i)
            pre[p][i] = x4[(row0 + i * 8 + rb) * (DIM / 4) + p * (DC / 4) + c4];

    for (int cc = 0; cc < NCH; cc += PD) {
#pragma unroll
        for (int p = 0; p < PD; ++p) {
            const int ch = cc + p;

            // Publish chunk ch to this wave's LDS (compiler waits pre[p]'s
            // vmcnt only -- newer chunks stay in flight).
#pragma unroll
            for (int i = 0; i < 8; ++i)
                lw[(i * 8 + rb) * RS4 + c4] = pre[p][i];

            // Refill pre[p] with chunk ch+PD (keeps issue continuous).
            if (ch + PD < NCH) {
#pragma unroll
                for (int i = 0; i < 8; ++i)
                    pre[p][i] = x4[(row0 + i * 8 + rb) * (DIM / 4)
                                   + (ch + PD) * (DC / 4) + c4];
            }

            // Compute chunk ch: own token's row from LDS, W via wave-uniform
            // (scalar-cache) loads.
#pragma unroll
            for (int j = 0; j < DC / 4; ++j) {
                float4 xv = lw[lane * RS4 + j];
                int d = ch * (DC / 4) + j;     // uniform across the wave
#pragma unroll
                for (int e = 0; e < NE; ++e) {
                    float4 wv = W4[e * (DIM / 4) + d];
                    acc[e] = fmaf(xv.x, wv.x, acc[e]);
                    acc[e] = fmaf(xv.y, wv.y, acc[e]);
                    acc[e] = fmaf(xv.z, wv.z, acc[e]);
                    acc[e] = fmaf(xv.w, wv.w, acc[e]);
                }
            }
        }
    }

    // Epilogue: bias, stable top-2 on logits (ties -> lower index first,
    // matches lax.top_k), softmax probs for the two winners.
    float logit[NE];
#pragma unroll
    for (int e = 0; e < NE; ++e) logit[e] = acc[e] + b[e];

    float v1 = -INFINITY, v2 = -INFINITY;
    int   i1 = 0,         i2 = 0;
#pragma unroll
    for (int e = 0; e < NE; ++e) {
        float v = logit[e];
        if (v > v1)      { v2 = v1; i2 = i1; v1 = v; i1 = e; }
        else if (v > v2) { v2 = v;  i2 = e; }
    }

    float sum = 0.f;
#pragma unroll
    for (int e = 0; e < NE; ++e) sum += __expf(logit[e] - v1);
    float inv = 1.0f / sum;
    float p1  = inv;                        // exp(v1 - v1) * inv
    float p2  = __expf(v2 - v1) * inv;

    int n = tok0 + t;
    float2* outi = (float2*)out;                            // indices (as float)
    float2* outv = (float2*)(out + 2 * (size_t)NUM_TOKENS); // values
    outi[n] = make_float2((float)i1, (float)i2);
    outv[n] = make_float2(p1, p2);
}

extern "C" void kernel_launch(void* const* d_in, const int* in_sizes, int n_in,
                              void* d_out, int out_size, void* d_ws, size_t ws_size,
                              hipStream_t stream) {
    const float* x = (const float*)d_in[0];
    const float* W = (const float*)d_in[1];
    const float* b = (const float*)d_in[2];
    float* out = (float*)d_out;

    dim3 grid(NUM_TOKENS / TPB);  // 512 blocks
    dim3 block(TPB);
    topk_gating_kernel<<<grid, block, 0, stream>>>(x, W, b, out);
}

// Round 3
// 802.280 us; speedup vs baseline: 1.1396x; 1.1396x over previous
//
#include <hip/hip_runtime.h>
#include <math.h>

// TopKGating: logits = x @ W^T + b  -> softmax(8) -> top-2 (indices, values)
// x: [131072, 1024] f32, W: [8, 1024] f32, b: [8] f32
// out: [N*2] indices (as float) then [N*2] values, flat concat.
//
// R3: wave-autonomous + NAMED-REGISTER double-buffer.
//  - R1/R2 post-mortem: float4 pre[][] was demoted to scratch (VGPR=92 vs
//    128 needed; WRITE_SIZE 525 MB == 4KB/thread of scratch writeback).
//    Every staged byte went HBM->reg->scratch->reg->LDS. Fix: 16 named
//    float4 variables (no alloca -> guaranteed registers).
//  - Keep R2's wave-autonomy: NO __syncthreads anywhere. Each wave owns 64
//    tokens + a private LDS region; within-wave ds-write->ds-read ordering
//    is program-order (lockstep wave, in-order DS pipe, compiler-tracked
//    aliasing), so no barrier-forced vmcnt(0) drain exists.
//  - 2-chunk pipeline: publish A (compiler waits vmcnt(8), B in flight),
//    reissue A for ch+2, compute ch; swap. Memory issue never idles.

#define NUM_TOKENS 131072
#define DIM        1024
#define NE         8
#define TPB        256            // 4 waves, thread == token
#define DC         32             // floats per token per chunk
#define NCH        (DIM / DC)     // 32 chunks
#define RS4        9              // LDS row stride in float4 (8 data + 1 pad);
                                  // measured SQ_LDS_BANK_CONFLICT == 0

__global__ __launch_bounds__(TPB)
void topk_gating_kernel(const float* __restrict__ x,
                        const float* __restrict__ W,
                        const float* __restrict__ b,
                        float* __restrict__ out)
{
    __shared__ float4 lds4[4][64 * RS4];   // 4 waves x 9216 B = 36864 B
    const int t    = threadIdx.x;
    const int lane = t & 63;
    const int w    = t >> 6;
    const int tok0 = blockIdx.x * TPB;

    const float4* x4 = (const float4*)x;   // [N, 256]
    const float4* W4 = (const float4*)W;   // [8, 256]
    float4* lw = lds4[w];                  // this wave's private region

    // Staging geometry: instr i covers token rows i*8 .. i*8+7 of this
    // wave's 64; 8 lanes x 128B contiguous per row -> full-line coalescing.
    const int rb   = lane >> 3;            // row within 8-row group
    const int c4   = lane & 7;             // float4 col within chunk
    const int row0 = tok0 + w * 64;        // this wave's first token

    // Per-thread global base; i-th staging load = xb[i*8*(DIM/4) + ch*(DC/4)].
    const float4* xb = x4 + (size_t)(row0 + rb) * (DIM / 4) + c4;

    float acc[NE];
#pragma unroll
    for (int e = 0; e < NE; ++e) acc[e] = 0.f;

    // Two named staging buffers (8 float4 each) -- NOT arrays.
    float4 sA0, sA1, sA2, sA3, sA4, sA5, sA6, sA7;
    float4 sB0, sB1, sB2, sB3, sB4, sB5, sB6, sB7;

#define ISSUE(p0,p1,p2,p3,p4,p5,p6,p7, CH) do {                  \
        const float4* _p = xb + (CH) * (DC / 4);                 \
        p0 = _p[0 * 8 * (DIM / 4)];                              \
        p1 = _p[1 * 8 * (DIM / 4)];                              \
        p2 = _p[2 * 8 * (DIM / 4)];                              \
        p3 = _p[3 * 8 * (DIM / 4)];                              \
        p4 = _p[4 * 8 * (DIM / 4)];                              \
        p5 = _p[5 * 8 * (DIM / 4)];                              \
        p6 = _p[6 * 8 * (DIM / 4)];                              \
        p7 = _p[7 * 8 * (DIM / 4)];                              \
    } while (0)

#define PUBLISH(p0,p1,p2,p3,p4,p5,p6,p7) do {                    \
        lw[(0 * 8 + rb) * RS4 + c4] = p0;                        \
        lw[(1 * 8 + rb) * RS4 + c4] = p1;                        \
        lw[(2 * 8 + rb) * RS4 + c4] = p2;                        \
        lw[(3 * 8 + rb) * RS4 + c4] = p3;                        \
        lw[(4 * 8 + rb) * RS4 + c4] = p4;                        \
        lw[(5 * 8 + rb) * RS4 + c4] = p5;                        \
        lw[(6 * 8 + rb) * RS4 + c4] = p6;                        \
        lw[(7 * 8 + rb) * RS4 + c4] = p7;                        \
    } while (0)

#define COMPUTE(CH) do {                                         \
        _Pragma("unroll")                                        \
        for (int j = 0; j < DC / 4; ++j) {                       \
            float4 xv = lw[lane * RS4 + j];                      \
            int d = (CH) * (DC / 4) + j;  /* wave-uniform */     \
            _Pragma("unroll")                                    \
            for (int e = 0; e < NE; ++e) {                       \
                float4 wv = W4[e * (DIM / 4) + d];               \
                acc[e] = fmaf(xv.x, wv.x, acc[e]);               \
                acc[e] = fmaf(xv.y, wv.y, acc[e]);               \
                acc[e] = fmaf(xv.z, wv.z, acc[e]);               \
                acc[e] = fmaf(xv.w, wv.w, acc[e]);               \
            }                                                    \
        }                                                        \
    } while (0)

    // Prologue: chunks 0 and 1 in flight.
    ISSUE(sA0,sA1,sA2,sA3,sA4,sA5,sA6,sA7, 0);
    ISSUE(sB0,sB1,sB2,sB3,sB4,sB5,sB6,sB7, 1);

    for (int cc = 0; cc < NCH; cc += 2) {
        // Publish chunk cc (waits only its own 8 loads; B stays in flight).
        PUBLISH(sA0,sA1,sA2,sA3,sA4,sA5,sA6,sA7);
        if (cc + 2 < NCH)
            ISSUE(sA0,sA1,sA2,sA3,sA4,sA5,sA6,sA7, cc + 2);
        COMPUTE(cc);

        PUBLISH(sB0,sB1,sB2,sB3,sB4,sB5,sB6,sB7);
        if (cc + 3 < NCH)
            ISSUE(sB0,sB1,sB2,sB3,sB4,sB5,sB6,sB7, cc + 3);
        COMPUTE(cc + 1);
    }

    // Epilogue: bias, stable top-2 on logits (ties -> lower index first,
    // matches lax.top_k), softmax probs for the two winners.
    float logit[NE];
#pragma unroll
    for (int e = 0; e < NE; ++e) logit[e] = acc[e] + b[e];

    float v1 = -INFINITY, v2 = -INFINITY;
    int   i1 = 0,         i2 = 0;
#pragma unroll
    for (int e = 0; e < NE; ++e) {
        float v = logit[e];
        if (v > v1)      { v2 = v1; i2 = i1; v1 = v; i1 = e; }
        else if (v > v2) { v2 = v;  i2 = e; }
    }

    float sum = 0.f;
#pragma unroll
    for (int e = 0; e < NE; ++e) sum += __expf(logit[e] - v1);
    float inv = 1.0f / sum;
    float p1  = inv;                        // exp(v1 - v1) * inv
    float p2  = __expf(v2 - v1) * inv;

    int n = tok0 + t;
    float2* outi = (float2*)out;                            // indices (as float)
    float2* outv = (float2*)(out + 2 * (size_t)NUM_TOKENS); // values
    outi[n] = make_float2((float)i1, (float)i2);
    outv[n] = make_float2(p1, p2);

#undef ISSUE
#undef PUBLISH
#undef COMPUTE
}

extern "C" void kernel_launch(void* const* d_in, const int* in_sizes, int n_in,
                              void* d_out, int out_size, void* d_ws, size_t ws_size,
                              hipStream_t stream) {
    const float* x = (const float*)d_in[0];
    const float* W = (const float*)d_in[1];
    const float* b = (const float*)d_in[2];
    float* out = (float*)d_out;

    dim3 grid(NUM_TOKENS / TPB);  // 512 blocks
    dim3 block(TPB);
    topk_gating_kernel<<<grid, block, 0, stream>>>(x, W, b, out);
}

// Round 6
// 754.944 us; speedup vs baseline: 1.2111x; 1.0627x over previous
//
#include <hip/hip_runtime.h>
#include <math.h>

// TopKGating: logits = x @ W^T + b  -> softmax(8) -> top-2 (indices, values)
// x: [131072, 1024] f32, W: [8, 1024] f32, b: [8] f32
// out: [N*2] indices (as float) then [N*2] values, flat concat.
//
// R6 == R4 theory, resubmit #2 (R4/R5 both died to container failures; no
// counters either time; source audited memory-safe + deadlock-free).
// Defensive diff vs R4: removed the __launch_bounds__(,4) min-waves hint --
// 4 blocks/CU is already guaranteed by LDS sizing (160KiB/40960B = 4) and
// VGPR (92 measured on the R3-lineage body <= 128 needed), so the hint only
// added an untested allocator constraint.
//
// R4: d-split wave pairs to double occupancy.
//  - R3 post-mortem: scratch eliminated but kernel stuck ~2 TB/s, same as
//    the barriered R0 structure. Shared limiter: thread=token caps the
//    kernel at 2048 waves = 2 waves/SIMD (Occupancy 23%) -- too thin to
//    hide load latency, regardless of pipeline structure.
//  - Fix: each 64-token group is serviced by TWO waves, one per 512-dim
//    half. 1024 blocks x 4 waves = 4096 waves = 4/SIMD (16/CU). One
//    end-of-kernel LDS combine merges partner partials; the streaming main
//    loop stays barrier-free with named-register double-buffered staging
//    (no arrays -> no scratch; measured 0 bank conflicts).

#define NUM_TOKENS 131072
#define DIM        1024
#define NE         8
#define TPB        256            // 4 waves
#define TOKPB      128            // tokens per block: two 64-token groups
#define HD         512            // dims per wave (half of DIM)
#define DC         32             // floats per token per chunk
#define NCH        (HD / DC)      // 16 chunks per wave
#define RS4        9              // LDS row stride in float4 (8 data + 1 pad)

__global__ __launch_bounds__(TPB)
void topk_gating_kernel(const float* __restrict__ x,
                        const float* __restrict__ W,
                        const float* __restrict__ b,
                        float* __restrict__ out)
{
    __shared__ float4 lds4[4][64 * RS4];   // 36864 B staging (per-wave private)
    __shared__ float  cmb[2][64][NE];      // 4096 B partial-combine buffer
    const int t    = threadIdx.x;
    const int lane = t & 63;
    const int w    = t >> 6;
    const int pair = w >> 1;               // which 64-token group (0/1)
    const int half = w & 1;                // which 512-dim half (0/1)
    const int row0 = blockIdx.x * TOKPB + pair * 64;

    const float4* x4 = (const float4*)x;   // [N, 256]
    const float4* W4 = (const float4*)W;   // [8, 256]
    float4* lw = lds4[w];                  // this wave's private region

    // Staging geometry: instr i covers token rows i*8 .. i*8+7 of this
    // wave's 64; 8 lanes x 128B contiguous per row -> coalesced.
    const int rb = lane >> 3;              // row within 8-row group
    const int c4 = lane & 7;               // float4 col within chunk

    // Per-thread global base inside this wave's [64 tok x 512 dim] panel.
    const float4* xb = x4 + (size_t)(row0 + rb) * (DIM / 4)
                          + half * (HD / 4) + c4;

    float acc[NE];
#pragma unroll
    for (int e = 0; e < NE; ++e) acc[e] = 0.f;

    // Two named staging buffers (8 float4 each) -- NOT arrays (scratch!).
    float4 sA0, sA1, sA2, sA3, sA4, sA5, sA6, sA7;
    float4 sB0, sB1, sB2, sB3, sB4, sB5, sB6, sB7;

#define ISSUE(p0,p1,p2,p3,p4,p5,p6,p7, CH) do {                  \
        const float4* _p = xb + (CH) * (DC / 4);                 \
        p0 = _p[0 * 8 * (DIM / 4)];                              \
        p1 = _p[1 * 8 * (DIM / 4)];                              \
        p2 = _p[2 * 8 * (DIM / 4)];                              \
        p3 = _p[3 * 8 * (DIM / 4)];                              \
        p4 = _p[4 * 8 * (DIM / 4)];                              \
        p5 = _p[5 * 8 * (DIM / 4)];                              \
        p6 = _p[6 * 8 * (DIM / 4)];                              \
        p7 = _p[7 * 8 * (DIM / 4)];                              \
    } while (0)

#define PUBLISH(p0,p1,p2,p3,p4,p5,p6,p7) do {                    \
        lw[(0 * 8 + rb) * RS4 + c4] = p0;                        \
        lw[(1 * 8 + rb) * RS4 + c4] = p1;                        \
        lw[(2 * 8 + rb) * RS4 + c4] = p2;                        \
        lw[(3 * 8 + rb) * RS4 + c4] = p3;                        \
        lw[(4 * 8 + rb) * RS4 + c4] = p4;                        \
        lw[(5 * 8 + rb) * RS4 + c4] = p5;                        \
        lw[(6 * 8 + rb) * RS4 + c4] = p6;                        \
        lw[(7 * 8 + rb) * RS4 + c4] = p7;                        \
    } while (0)

#define COMPUTE(CH) do {                                         \
        _Pragma("unroll")                                        \
        for (int j = 0; j < DC / 4; ++j) {                       \
            float4 xv = lw[lane * RS4 + j];                      \
            int d = half * (HD / 4) + (CH) * (DC / 4) + j;       \
            _Pragma("unroll")                                    \
            for (int e = 0; e < NE; ++e) {                       \
                float4 wv = W4[e * (DIM / 4) + d];               \
                acc[e] = fmaf(xv.x, wv.x, acc[e]);               \
                acc[e] = fmaf(xv.y, wv.y, acc[e]);               \
                acc[e] = fmaf(xv.z, wv.z, acc[e]);               \
                acc[e] = fmaf(xv.w, wv.w, acc[e]);               \
            }                                                    \
        }                                                        \
    } while (0)

    // Prologue: chunks 0 and 1 in flight.
    ISSUE(sA0,sA1,sA2,sA3,sA4,sA5,sA6,sA7, 0);
    ISSUE(sB0,sB1,sB2,sB3,sB4,sB5,sB6,sB7, 1);

    for (int cc = 0; cc < NCH; cc += 2) {
        // Publish chunk cc (waits only its own 8 loads; B stays in flight).
        PUBLISH(sA0,sA1,sA2,sA3,sA4,sA5,sA6,sA7);
        if (cc + 2 < NCH)
            ISSUE(sA0,sA1,sA2,sA3,sA4,sA5,sA6,sA7, cc + 2);
        COMPUTE(cc);

        PUBLISH(sB0,sB1,sB2,sB3,sB4,sB5,sB6,sB7);
        if (cc + 3 < NCH)
            ISSUE(sB0,sB1,sB2,sB3,sB4,sB5,sB6,sB7, cc + 3);
        COMPUTE(cc + 1);
    }

    // Combine partner halves, then epilogue on the even wave.
    if (half == 1) {
#pragma unroll
        for (int e = 0; e < NE; ++e) cmb[pair][lane][e] = acc[e];
    }
    __syncthreads();
    if (half == 0) {
        float logit[NE];
#pragma unroll
        for (int e = 0; e < NE; ++e)
            logit[e] = acc[e] + cmb[pair][lane][e] + b[e];

        // Stable top-2 (ties -> lower index first, matches lax.top_k).
        float v1 = -INFINITY, v2 = -INFINITY;
        int   i1 = 0,         i2 = 0;
#pragma unroll
        for (int e = 0; e < NE; ++e) {
            float v = logit[e];
            if (v > v1)      { v2 = v1; i2 = i1; v1 = v; i1 = e; }
            else if (v > v2) { v2 = v;  i2 = e; }
        }

        float sum = 0.f;
#pragma unroll
        for (int e = 0; e < NE; ++e) sum += __expf(logit[e] - v1);
        float inv = 1.0f / sum;
        float p1  = inv;                        // exp(v1 - v1) * inv
        float p2  = __expf(v2 - v1) * inv;

        int n = row0 + lane;
        float2* outi = (float2*)out;                            // indices
        float2* outv = (float2*)(out + 2 * (size_t)NUM_TOKENS); // values
        outi[n] = make_float2((float)i1, (float)i2);
        outv[n] = make_float2(p1, p2);
    }

#undef ISSUE
#undef PUBLISH
#undef COMPUTE
}

extern "C" void kernel_launch(void* const* d_in, const int* in_sizes, int n_in,
                              void* d_out, int out_size, void* d_ws, size_t ws_size,
                              hipStream_t stream) {
    const float* x = (const float*)d_in[0];
    const float* W = (const float*)d_in[1];
    const float* b = (const float*)d_in[2];
    float* out = (float*)d_out;

    dim3 grid(NUM_TOKENS / TOKPB);  // 1024 blocks
    dim3 block(TPB);
    topk_gating_kernel<<<grid, block, 0, stream>>>(x, W, b, out);
}

// Round 7
// 723.742 us; speedup vs baseline: 1.2633x; 1.0431x over previous
//
#include <hip/hip_runtime.h>
#include <math.h>

// TopKGating: logits = x @ W^T + b  -> softmax(8) -> top-2 (indices, values)
// x: [131072, 1024] f32, W: [8, 1024] f32, b: [8] f32
// out: [N*2] indices (as float) then [N*2] values, flat concat.
//
// R7: W in LDS -- kill the vmcnt poisoning.
//  - R6 post-mortem: occupancy 2x gave only ~15%; all structures converge
//    ~2.2 TB/s. Shared limiter found in COMPUTE: 64 per-chunk W loads are
//    VECTOR memory ops (compiler can't prove d wave-uniform), and vmcnt
//    completes IN ORDER -> every W-load wait drains the older deep-prefetch
//    x loads (~900cy), then 2048 W loads/thread serialize at ~L2 latency.
//    The x pipeline never mattered; W vmem was the critical path.
//  - Fix: preload W (32 KB) into LDS once; inner-loop W reads are ds_read
//    broadcasts (uniform address, lgkmcnt) -- decoupled from the x vmcnt
//    queue. Main loop has NO vmem except the 16 pipelined x loads.
//  - Structure: R3 shape (512 blocks x 4 waves, wave owns 64 tok x 1024 d,
//    barrier-free main loop, named-register double buffer, RS4=9 staging
//    pad -- measured 0 bank conflicts). One __syncthreads after W preload.
//    LDS total 69632 B == R1's proven size.

#define NUM_TOKENS 131072
#define DIM        1024
#define NE         8
#define TPB        256            // 4 waves, thread == token
#define DC         32             // floats per token per chunk
#define NCH        (DIM / DC)     // 32 chunks
#define RS4        9              // LDS row stride in float4 (8 data + 1 pad)

__global__ __launch_bounds__(TPB)
void topk_gating_kernel(const float* __restrict__ x,
                        const float* __restrict__ W,
                        const float* __restrict__ b,
                        float* __restrict__ out)
{
    __shared__ float4 lds4[4][64 * RS4];   // 36864 B staging (per-wave private)
    __shared__ float4 wlds[NE * (DIM / 4)]; // 32768 B: whole W, [8][256] float4
    const int t    = threadIdx.x;
    const int lane = t & 63;
    const int w    = t >> 6;
    const int tok0 = blockIdx.x * TPB;

    const float4* x4 = (const float4*)x;   // [N, 256]
    const float4* W4 = (const float4*)W;   // [8, 256]
    float4* lw = lds4[w];                  // this wave's private region

    // --- W preload: 2048 float4 / 256 threads = 8 each, coalesced. ---
#pragma unroll
    for (int i = 0; i < NE * (DIM / 4) / TPB; ++i)
        wlds[i * TPB + t] = W4[i * TPB + t];

    // Staging geometry: instr i covers token rows i*8 .. i*8+7 of this
    // wave's 64; 8 lanes x 128B contiguous per row -> coalesced.
    const int rb   = lane >> 3;            // row within 8-row group
    const int c4   = lane & 7;             // float4 col within chunk
    const int row0 = tok0 + w * 64;        // this wave's first token

    // Per-thread global base; i-th staging load = xb[i*8*(DIM/4) + ch*(DC/4)].
    const float4* xb = x4 + (size_t)(row0 + rb) * (DIM / 4) + c4;

    float acc[NE];
#pragma unroll
    for (int e = 0; e < NE; ++e) acc[e] = 0.f;

    // Two named staging buffers (8 float4 each) -- NOT arrays (scratch!).
    float4 sA0, sA1, sA2, sA3, sA4, sA5, sA6, sA7;
    float4 sB0, sB1, sB2, sB3, sB4, sB5, sB6, sB7;

#define ISSUE(p0,p1,p2,p3,p4,p5,p6,p7, CH) do {                  \
        const float4* _p = xb + (CH) * (DC / 4);                 \
        p0 = _p[0 * 8 * (DIM / 4)];                              \
        p1 = _p[1 * 8 * (DIM / 4)];                              \
        p2 = _p[2 * 8 * (DIM / 4)];                              \
        p3 = _p[3 * 8 * (DIM / 4)];                              \
        p4 = _p[4 * 8 * (DIM / 4)];                              \
        p5 = _p[5 * 8 * (DIM / 4)];                              \
        p6 = _p[6 * 8 * (DIM / 4)];                              \
        p7 = _p[7 * 8 * (DIM / 4)];                              \
    } while (0)

#define PUBLISH(p0,p1,p2,p3,p4,p5,p6,p7) do {                    \
        lw[(0 * 8 + rb) * RS4 + c4] = p0;                        \
        lw[(1 * 8 + rb) * RS4 + c4] = p1;                        \
        lw[(2 * 8 + rb) * RS4 + c4] = p2;                        \
        lw[(3 * 8 + rb) * RS4 + c4] = p3;                        \
        lw[(4 * 8 + rb) * RS4 + c4] = p4;                        \
        lw[(5 * 8 + rb) * RS4 + c4] = p5;                        \
        lw[(6 * 8 + rb) * RS4 + c4] = p6;                        \
        lw[(7 * 8 + rb) * RS4 + c4] = p7;                        \
    } while (0)

#define COMPUTE(CH) do {                                         \
        _Pragma("unroll")                                        \
        for (int j = 0; j < DC / 4; ++j) {                       \
            float4 xv = lw[lane * RS4 + j];                      \
            int d = (CH) * (DC / 4) + j;   /* block-uniform */   \
            _Pragma("unroll")                                    \
            for (int e = 0; e < NE; ++e) {                       \
                float4 wv = wlds[e * (DIM / 4) + d];             \
                acc[e] = fmaf(xv.x, wv.x, acc[e]);               \
                acc[e] = fmaf(xv.y, wv.y, acc[e]);               \
                acc[e] = fmaf(xv.z, wv.z, acc[e]);               \
                acc[e] = fmaf(xv.w, wv.w, acc[e]);               \
            }                                                    \
        }                                                        \
    } while (0)

    // Prologue: chunks 0 and 1 in flight (issued before the W barrier so
    // HBM latency overlaps the preload/sync).
    ISSUE(sA0,sA1,sA2,sA3,sA4,sA5,sA6,sA7, 0);
    ISSUE(sB0,sB1,sB2,sB3,sB4,sB5,sB6,sB7, 1);

    __syncthreads();   // wlds visible to all waves

    for (int cc = 0; cc < NCH; cc += 2) {
        // Publish chunk cc (waits only its own 8 loads; B stays in flight).
        PUBLISH(sA0,sA1,sA2,sA3,sA4,sA5,sA6,sA7);
        if (cc + 2 < NCH)
            ISSUE(sA0,sA1,sA2,sA3,sA4,sA5,sA6,sA7, cc + 2);
        COMPUTE(cc);

        PUBLISH(sB0,sB1,sB2,sB3,sB4,sB5,sB6,sB7);
        if (cc + 3 < NCH)
            ISSUE(sB0,sB1,sB2,sB3,sB4,sB5,sB6,sB7, cc + 3);
        COMPUTE(cc + 1);
    }

    // Epilogue: bias, stable top-2 on logits (ties -> lower index first,
    // matches lax.top_k), softmax probs for the two winners.
    float logit[NE];
#pragma unroll
    for (int e = 0; e < NE; ++e) logit[e] = acc[e] + b[e];

    float v1 = -INFINITY, v2 = -INFINITY;
    int   i1 = 0,         i2 = 0;
#pragma unroll
    for (int e = 0; e < NE; ++e) {
        float v = logit[e];
        if (v > v1)      { v2 = v1; i2 = i1; v1 = v; i1 = e; }
        else if (v > v2) { v2 = v;  i2 = e; }
    }

    float sum = 0.f;
#pragma unroll
    for (int e = 0; e < NE; ++e) sum += __expf(logit[e] - v1);
    float inv = 1.0f / sum;
    float p1  = inv;                        // exp(v1 - v1) * inv
    float p2  = __expf(v2 - v1) * inv;

    int n = tok0 + t;
    float2* outi = (float2*)out;                            // indices (as float)
    float2* outv = (float2*)(out + 2 * (size_t)NUM_TOKENS); // values
    outi[n] = make_float2((float)i1, (float)i2);
    outv[n] = make_float2(p1, p2);

#undef ISSUE
#undef PUBLISH
#undef COMPUTE
}

extern "C" void kernel_launch(void* const* d_in, const int* in_sizes, int n_in,
                              void* d_out, int out_size, void* d_ws, size_t ws_size,
                              hipStream_t stream) {
    const float* x = (const float*)d_in[0];
    const float* W = (const float*)d_in[1];
    const float* b = (const float*)d_in[2];
    float* out = (float*)d_out;

    dim3 grid(NUM_TOKENS / TPB);  // 512 blocks
    dim3 block(TPB);
    topk_gating_kernel<<<grid, block, 0, stream>>>(x, W, b, out);
}